// Round 1
// baseline (899.066 us; speedup 1.0000x reference)
//
#include <hip/hip_runtime.h>

#define VN_EPS 1e-12f

// Phase 1: per-face normal computation + atomic scatter-add to vertex accumulators.
__global__ void vn_face_scatter(const float* __restrict__ v,
                                const int* __restrict__ faces,
                                float* __restrict__ vn,
                                int n_faces) {
    int f = blockIdx.x * blockDim.x + threadIdx.x;
    if (f >= n_faces) return;

    int i0 = faces[3 * f + 0];
    int i1 = faces[3 * f + 1];
    int i2 = faces[3 * f + 2];

    float v0x = v[3 * i0 + 0], v0y = v[3 * i0 + 1], v0z = v[3 * i0 + 2];
    float v1x = v[3 * i1 + 0], v1y = v[3 * i1 + 1], v1z = v[3 * i1 + 2];
    float v2x = v[3 * i2 + 0], v2y = v[3 * i2 + 1], v2z = v[3 * i2 + 2];

    // e0 = v1 - v0, e1 = v2 - v1, e2 = v0 - v2
    float e0x = v1x - v0x, e0y = v1y - v0y, e0z = v1z - v0z;
    float e1x = v2x - v1x, e1y = v2y - v1y, e1z = v2z - v1z;
    float e2x = v0x - v2x, e2y = v0y - v2y, e2z = v0z - v2z;

    // cross(e0,e1) + cross(e1,e2) + cross(e2,e0)  (matches reference numerics)
    float nx = (e0y * e1z - e0z * e1y) + (e1y * e2z - e1z * e2y) + (e2y * e0z - e2z * e0y);
    float ny = (e0z * e1x - e0x * e1z) + (e1z * e2x - e1x * e2z) + (e2z * e0x - e2x * e0z);
    float nz = (e0x * e1y - e0y * e1x) + (e1x * e2y - e1y * e2x) + (e2x * e0y - e2y * e0x);

    atomicAdd(&vn[3 * i0 + 0], nx);
    atomicAdd(&vn[3 * i0 + 1], ny);
    atomicAdd(&vn[3 * i0 + 2], nz);
    atomicAdd(&vn[3 * i1 + 0], nx);
    atomicAdd(&vn[3 * i1 + 1], ny);
    atomicAdd(&vn[3 * i1 + 2], nz);
    atomicAdd(&vn[3 * i2 + 0], nx);
    atomicAdd(&vn[3 * i2 + 1], ny);
    atomicAdd(&vn[3 * i2 + 2], nz);
}

// Phase 2: normalize. LDS-staged so global loads/stores are fully coalesced.
__global__ void vn_normalize(float* __restrict__ vn, int n_verts) {
    __shared__ float s[3 * 256];
    int base = blockIdx.x * 256 * 3;
    int total = n_verts * 3;

    #pragma unroll
    for (int k = 0; k < 3; ++k) {
        int idx = base + k * 256 + threadIdx.x;
        if (idx < total) s[k * 256 + threadIdx.x] = vn[idx];
    }
    __syncthreads();

    int vtx = blockIdx.x * 256 + threadIdx.x;
    if (vtx < n_verts) {
        float x = s[3 * threadIdx.x + 0];
        float y = s[3 * threadIdx.x + 1];
        float z = s[3 * threadIdx.x + 2];
        float norm = sqrtf(x * x + y * y + z * z);
        float inv = 1.0f / fmaxf(norm, VN_EPS);
        s[3 * threadIdx.x + 0] = x * inv;
        s[3 * threadIdx.x + 1] = y * inv;
        s[3 * threadIdx.x + 2] = z * inv;
    }
    __syncthreads();

    #pragma unroll
    for (int k = 0; k < 3; ++k) {
        int idx = base + k * 256 + threadIdx.x;
        if (idx < total) vn[idx] = s[k * 256 + threadIdx.x];
    }
}

extern "C" void kernel_launch(void* const* d_in, const int* in_sizes, int n_in,
                              void* d_out, int out_size, void* d_ws, size_t ws_size,
                              hipStream_t stream) {
    const float* v = (const float*)d_in[0];
    const int* faces = (const int*)d_in[1];
    float* vn = (float*)d_out;

    int n_verts = in_sizes[0] / 3;
    int n_faces = in_sizes[1] / 3;

    // Zero the accumulator (d_out) — harness poisons it, and we accumulate in place.
    hipMemsetAsync(vn, 0, (size_t)out_size * sizeof(float), stream);

    int block = 256;
    int grid_f = (n_faces + block - 1) / block;
    vn_face_scatter<<<grid_f, block, 0, stream>>>(v, faces, vn, n_faces);

    int grid_v = (n_verts + block - 1) / block;
    vn_normalize<<<grid_v, block, 0, stream>>>(vn, n_verts);
}